// Round 3
// baseline (471.322 us; speedup 1.0000x reference)
//
#include <hip/hip_runtime.h>
#include <stdint.h>

#define BB 32
#define SS 8400
#define LL 80
#define DD 256
#define KK 300

// monotone map f32 -> u32, DESCENDING float order (unique per bit pattern)
__device__ __forceinline__ uint32_t f32_desc_ord(float f) {
    uint32_t u = __builtin_bit_cast(uint32_t, f);
    uint32_t asc = (u & 0x80000000u) ? ~u : (u | 0x80000000u);
    return ~asc;
}

// Kernel 1: per (b,s) row: key32 = desc-ord of max over 80 f32 labels
__global__ __launch_bounds__(256) void k_scores(const float* __restrict__ cls,
                                                uint32_t* __restrict__ keys32) {
    int r = blockIdx.x * 256 + threadIdx.x;   // r in [0, B*S)
    const float4* row = (const float4*)(cls + (size_t)r * LL);  // 320B, 16B-aligned
    float m = -3.4e38f;
#pragma unroll
    for (int i = 0; i < 20; ++i) {
        float4 v = row[i];
        m = fmaxf(m, fmaxf(fmaxf(v.x, v.y), fmaxf(v.z, v.w)));
    }
    keys32[r] = f32_desc_ord(m);
}

// Kernel 2: one block per batch. key64 = (desc32 << 32) | s  (unique; stable
// lax.top_k semantics: score descending, index ascending on exact ties).
// 8-pass radix select of the KK-th smallest key, compact, bitonic sort.
__global__ __launch_bounds__(256) void k_topk(const uint32_t* __restrict__ keys32,
                                              int* __restrict__ topk) {
    __shared__ unsigned long long keys[SS];    // 67,200 B
    __shared__ uint32_t hist[256];
    __shared__ unsigned long long sel[512];
    __shared__ unsigned long long sh_prefix;
    __shared__ uint32_t sh_k, sh_cnt;

    const int b = blockIdx.x;
    const int tid = threadIdx.x;
    const uint32_t* src = keys32 + (size_t)b * SS;

    for (int i = tid; i < SS; i += 256)
        keys[i] = ((unsigned long long)src[i] << 32) | (uint32_t)i;
    if (tid == 0) { sh_prefix = 0ull; sh_k = KK; sh_cnt = 0; }
    __syncthreads();

    for (int pos = 56; pos >= 0; pos -= 8) {
        hist[tid] = 0;
        __syncthreads();
        unsigned long long pref = sh_prefix;
        for (int i = tid; i < SS; i += 256) {
            unsigned long long key = keys[i];
            if (pos == 56 || (key >> (pos + 8)) == pref)   // short-circuit guards shift==64
                atomicAdd(&hist[(uint32_t)(key >> pos) & 0xFFu], 1u);
        }
        __syncthreads();
        if (tid == 0) {
            uint32_t k = sh_k, cum = 0, d;
            for (d = 0; d < 256u; ++d) {
                if (cum + hist[d] >= k) break;
                cum += hist[d];
            }
            sh_k = k - cum;
            sh_prefix = (pref << 8) | d;
        }
        __syncthreads();
    }
    const unsigned long long T = sh_prefix;   // exact KK-th smallest key (unique)

    for (int i = tid; i < SS; i += 256) {
        unsigned long long key = keys[i];
        if (key <= T) {
            uint32_t p = atomicAdd(&sh_cnt, 1u);
            if (p < 512u) sel[p] = key;
        }
    }
    __syncthreads();
    uint32_t cnt = sh_cnt;
    if (cnt > 512u) cnt = 512u;
    for (int i = tid; i < 512; i += 256)
        if ((uint32_t)i >= cnt) sel[i] = ~0ull;

    // bitonic sort 512 x u64 ascending
    for (int k2 = 2; k2 <= 512; k2 <<= 1) {
        for (int j = k2 >> 1; j > 0; j >>= 1) {
            __syncthreads();
            for (int i = tid; i < 512; i += 256) {
                int ixj = i ^ j;
                if (ixj > i) {
                    unsigned long long a = sel[i], c = sel[ixj];
                    bool asc2 = ((i & k2) == 0);
                    if ((a > c) == asc2) { sel[i] = c; sel[ixj] = a; }
                }
            }
        }
    }
    __syncthreads();
    for (int i = tid; i < KK; i += 256)
        topk[b * KK + i] = (int)(uint32_t)(sel[i] & 0xFFFFFFFFull);
}

// Kernel 3: gather rows. One block per (b,q), 64 threads. All f32.
__global__ __launch_bounds__(64) void k_gather(const float* __restrict__ coord,
                                               const float* __restrict__ cls,
                                               const float* __restrict__ mem,
                                               const int* __restrict__ topk,
                                               float* __restrict__ out) {
    const int r = blockIdx.x;          // b*KK + q
    const int b = r / KK;
    const int t = threadIdx.x;
    const int idx = topk[r];
    const size_t srow = (size_t)b * SS + (size_t)idx;

    // out layout (f32 elements): o0 refpts @0 (B*K*4) | o1 target (B*K*256) |
    //                            o2 logits (B*K*80)   | o3 bboxes (B*K*4)
    const size_t O1 = (size_t)BB * KK * 4;
    const size_t O2 = O1 + (size_t)BB * KK * DD;
    const size_t O3 = O2 + (size_t)BB * KK * LL;

    // target: 256 f32 = 64 lanes x float4
    {
        const float4* s = (const float4*)(mem + srow * DD);
        float4* d = (float4*)(out + O1 + (size_t)r * DD);
        d[t] = s[t];
    }
    // logits: 80 f32 = 20 lanes x float4
    if (t < 20) {
        const float4* s = (const float4*)(cls + srow * LL);
        float4* d = (float4*)(out + O2 + (size_t)r * LL);
        d[t] = s[t];
    }
    // coords: 4 f32 -> refpts verbatim copy + sigmoid -> bboxes
    if (t == 0) {
        float4 v = *(const float4*)(coord + srow * 4);
        *(float4*)(out + (size_t)r * 4) = v;
        float4 o;
        o.x = 1.0f / (1.0f + expf(-v.x));
        o.y = 1.0f / (1.0f + expf(-v.y));
        o.z = 1.0f / (1.0f + expf(-v.z));
        o.w = 1.0f / (1.0f + expf(-v.w));
        *(float4*)(out + O3 + (size_t)r * 4) = o;
    }
}

extern "C" void kernel_launch(void* const* d_in, const int* in_sizes, int n_in,
                              void* d_out, int out_size, void* d_ws, size_t ws_size,
                              hipStream_t stream) {
    const float* cls   = (const float*)d_in[0];  // (B,S,80) f32
    const float* coord = (const float*)d_in[1];  // (B,S,4) f32
    const float* mem   = (const float*)d_in[2];  // (B,S,256) f32
    // d_in[3] sources_last_element: unused by the reference
    float* out = (float*)d_out;

    uint32_t* keys32 = (uint32_t*)d_ws;                         // B*S u32 = 1,075,200 B
    int* topk = (int*)((char*)d_ws + (size_t)BB * SS * 4);      // B*K int

    k_scores<<<(BB * SS) / 256, 256, 0, stream>>>(cls, keys32);
    k_topk<<<BB, 256, 0, stream>>>(keys32, topk);
    k_gather<<<BB * KK, 64, 0, stream>>>(coord, cls, mem, topk, out);
}